// Round 1
// baseline (489.806 us; speedup 1.0000x reference)
//
#include <hip/hip_runtime.h>

// Geometry fixed by setup_inputs: [16, 1, 352, 1216] fp32.
#define BATCH 16
#define HH    352
#define WW    1216
#define IMG   (HH * WW)
#define QPR   (WW / 4)       // 304 quads (float4 groups) per row
#define BLOCK 320            // 5 waves; covers one full row (304 quads + 16 idle)
#define NWAVE (BLOCK / 64)
#define NBLK  (BATCH * HH)   // one block per image-row = 5632 (divisible by 8)
#define NXCD  8
#define CHUNK (NBLK / NXCD)  // 704

__device__ __forceinline__ float med3f(float a, float b, float c) {
#if defined(__has_builtin) && __has_builtin(__builtin_amdgcn_fmed3f)
    return __builtin_amdgcn_fmed3f(a, b, c);
#else
    return fmaxf(fminf(fmaxf(a, b), c), fminf(a, b));
#endif
}

// Bijective XCD swizzle: blocks land on XCDs round-robin by linear id, so
// id -> (id%8)*CHUNK + id/8 gives each XCD a contiguous run of image-rows.
// Rows r-1, r, r+1 are then consecutive blocks on the SAME XCD -> L2 hits.
__device__ __forceinline__ int swizzle_row(int i) {
    return (i & (NXCD - 1)) * CHUNK + (i >> 3);
}

// Load cols [c0-1 .. c0+4] of row h into o[6], zero-padded at image edges.
// c0 is pre-clamped to [0, WW-4] by the caller, so all addresses are in-row.
__device__ __forceinline__ void load_row6(const float* __restrict__ img, int h,
                                          int c0, float o[6]) {
    const bool hv = ((unsigned)h < (unsigned)HH);
    const float* r = img + (hv ? h : 0) * WW;
    float4 v = *reinterpret_cast<const float4*>(r + c0);
    float l  = r[max(c0 - 1, 0)];
    float rt = r[min(c0 + 4, WW - 1)];
    o[1] = hv ? v.x : 0.f;
    o[2] = hv ? v.y : 0.f;
    o[3] = hv ? v.z : 0.f;
    o[4] = hv ? v.w : 0.f;
    o[0] = (hv && c0 > 0)      ? l  : 0.f;
    o[5] = (hv && c0 + 4 < WW) ? rt : 0.f;
}

// contrast[i] = center - exact median3x3, for 4 pixels, from 3 row segments.
// Column sort3 (5 ops/col) + med3(max3(lo), med3(mid), min3(hi)) per pixel.
__device__ __forceinline__ void contrast4(const float rp[6], const float rc[6],
                                          const float rn[6], float c[4]) {
    float lo[6], mid[6], hi[6];
#pragma unroll
    for (int j = 0; j < 6; ++j) {
        float a = rp[j], b = rc[j], d = rn[j];
        float t0 = fminf(a, b), t1 = fmaxf(a, b);
        float t2 = fminf(t1, d);
        hi[j]  = fmaxf(t1, d);
        lo[j]  = fminf(t0, t2);
        mid[j] = fmaxf(t0, t2);
    }
#pragma unroll
    for (int i = 0; i < 4; ++i) {
        float mx = fmaxf(fmaxf(lo[i], lo[i + 1]), lo[i + 2]);
        float md = med3f(mid[i], mid[i + 1], mid[i + 2]);
        float mn = fminf(fminf(hi[i], hi[i + 1]), hi[i + 2]);
        c[i] = rc[i + 1] - med3f(mx, md, mn);
    }
}

__device__ __forceinline__ float waveRed(float v) {
#pragma unroll
    for (int o = 32; o > 0; o >>= 1) v += __shfl_down(v, o, 64);
    return v;
}

// Pass 1: per-image sums of {mask, mask*|pred_contrast|, mask*|target_contrast|}.
// One block per image-row; all stencil loads issued up-front (full MLP).
__global__ __launch_bounds__(BLOCK) void pass1(const float* __restrict__ pred,
                                               const float* __restrict__ tgt,
                                               const float* __restrict__ mask,
                                               float* __restrict__ sums) {
    const int f = swizzle_row(blockIdx.x);
    const int b = f / HH;
    const int h = f % HH;
    const int q = threadIdx.x;
    const int c0 = min(q * 4, WW - 4);
    const bool qv = q < QPR;

    const float* pimg = pred + b * IMG;
    const float* timg = tgt  + b * IMG;

    float P0[6], P1[6], P2[6], T0[6], T1[6], T2[6];
    load_row6(pimg, h - 1, c0, P0);
    load_row6(pimg, h,     c0, P1);
    load_row6(pimg, h + 1, c0, P2);
    load_row6(timg, h - 1, c0, T0);
    load_row6(timg, h,     c0, T1);
    load_row6(timg, h + 1, c0, T2);
    float4 m4 = *reinterpret_cast<const float4*>(mask + b * IMG + h * WW + c0);

    float pc[4], tc[4];
    contrast4(P0, P1, P2, pc);
    contrast4(T0, T1, T2, tc);

    float s_m = 0.f, s_p = 0.f, s_t = 0.f;
    float mv[4] = {m4.x, m4.y, m4.z, m4.w};
#pragma unroll
    for (int k = 0; k < 4; ++k) {
        s_m += mv[k];
        s_p += mv[k] * fabsf(pc[k]);
        s_t += mv[k] * fabsf(tc[k]);
    }
    if (!qv) { s_m = 0.f; s_p = 0.f; s_t = 0.f; }

    s_m = waveRed(s_m); s_p = waveRed(s_p); s_t = waveRed(s_t);

    __shared__ float red[3][NWAVE];
    const int lane = threadIdx.x & 63, wid = threadIdx.x >> 6;
    if (lane == 0) { red[0][wid] = s_m; red[1][wid] = s_p; red[2][wid] = s_t; }
    __syncthreads();
    if (threadIdx.x == 0) {
        float a0 = 0.f, a1 = 0.f, a2 = 0.f;
#pragma unroll
        for (int w = 0; w < NWAVE; ++w) { a0 += red[0][w]; a1 += red[1][w]; a2 += red[2][w]; }
        atomicAdd(&sums[b * 3 + 0], a0);
        atomicAdd(&sums[b * 3 + 1], a1);
        atomicAdd(&sums[b * 3 + 2], a2);
    }
}

// Pass 2: per-image sum of |pc/mean_pred - tc/mean_target|, with the final
// scalar division folded in via a device-scope last-block counter.
__global__ __launch_bounds__(BLOCK) void pass2(const float* __restrict__ pred,
                                               const float* __restrict__ tgt,
                                               const float* __restrict__ sums,
                                               float* __restrict__ acc,
                                               unsigned int* __restrict__ ctr,
                                               float* __restrict__ out) {
    const int f = swizzle_row(blockIdx.x);
    const int b = f / HH;
    const int h = f % HH;
    const int q = threadIdx.x;
    const int c0 = min(q * 4, WW - 4);
    const bool qv = q < QPR;

    const float denom  = sums[b * 3 + 0];
    const float inv_mp = denom / sums[b * 3 + 1];
    const float inv_mt = denom / sums[b * 3 + 2];

    const float* pimg = pred + b * IMG;
    const float* timg = tgt  + b * IMG;

    float P0[6], P1[6], P2[6], T0[6], T1[6], T2[6];
    load_row6(pimg, h - 1, c0, P0);
    load_row6(pimg, h,     c0, P1);
    load_row6(pimg, h + 1, c0, P2);
    load_row6(timg, h - 1, c0, T0);
    load_row6(timg, h,     c0, T1);
    load_row6(timg, h + 1, c0, T2);

    float pc[4], tc[4];
    contrast4(P0, P1, P2, pc);
    contrast4(T0, T1, T2, tc);

    float s = 0.f;
#pragma unroll
    for (int k = 0; k < 4; ++k)
        s += fabsf(pc[k] * inv_mp - tc[k] * inv_mt);
    if (!qv) s = 0.f;

    s = waveRed(s);

    __shared__ float red[NWAVE];
    const int lane = threadIdx.x & 63, wid = threadIdx.x >> 6;
    if (lane == 0) red[wid] = s;
    __syncthreads();
    if (threadIdx.x == 0) {
        float a = 0.f;
#pragma unroll
        for (int w = 0; w < NWAVE; ++w) a += red[w];
        atomicAdd(&acc[b], a);
        __threadfence();
        unsigned int old = __hip_atomic_fetch_add(ctr, 1u, __ATOMIC_ACQ_REL,
                                                  __HIP_MEMORY_SCOPE_AGENT);
        if (old == (unsigned)(NBLK - 1)) {
            // Last block: all atomics are globally visible (acq_rel + fence).
            float tm = 0.f, ta = 0.f;
            for (int i = 0; i < BATCH; ++i) {
                tm += __hip_atomic_load(&sums[i * 3 + 0], __ATOMIC_RELAXED,
                                        __HIP_MEMORY_SCOPE_AGENT);
                ta += __hip_atomic_load(&acc[i], __ATOMIC_RELAXED,
                                        __HIP_MEMORY_SCOPE_AGENT);
            }
            out[0] = ta / tm;
        }
    }
}

extern "C" void kernel_launch(void* const* d_in, const int* in_sizes, int n_in,
                              void* d_out, int out_size, void* d_ws, size_t ws_size,
                              hipStream_t stream) {
    const float* pred = (const float*)d_in[0];
    const float* tgt  = (const float*)d_in[1];
    const float* mask = (const float*)d_in[2];
    float* out = (float*)d_out;
    float* ws  = (float*)d_ws;  // [0..47] per-image {Sm,Sp,St}; [48..63] loss acc; [64] ctr

    hipMemsetAsync(d_ws, 0, 512, stream);

    dim3 grid(NBLK), blk(BLOCK);
    pass1<<<grid, blk, 0, stream>>>(pred, tgt, mask, ws);
    pass2<<<grid, blk, 0, stream>>>(pred, tgt, ws, ws + 48,
                                    (unsigned int*)(ws + 64), out);
}

// Round 2
// 292.010 us; speedup vs baseline: 1.6774x; 1.6774x over previous
//
#include <hip/hip_runtime.h>

// Geometry fixed by setup_inputs: [16, 1, 352, 1216] fp32.
#define BATCH 16
#define HH    352
#define WW    1216
#define IMG   (HH * WW)
#define QPR   (WW / 4)       // 304 quads (float4 groups) per row
#define BLOCK 320            // 5 waves; covers one full row (304 quads + 16 idle)
#define NWAVE (BLOCK / 64)
#define NBLK  (BATCH * HH)   // one block per image-row = 5632 (divisible by 8)
#define NXCD  8
#define CHUNK (NBLK / NXCD)  // 704

__device__ __forceinline__ float med3f(float a, float b, float c) {
#if defined(__has_builtin) && __has_builtin(__builtin_amdgcn_fmed3f)
    return __builtin_amdgcn_fmed3f(a, b, c);
#else
    return fmaxf(fminf(fmaxf(a, b), c), fminf(a, b));
#endif
}

// Bijective XCD swizzle: hardware assigns block i to XCD i%8, so
// i -> (i%8)*CHUNK + i/8 gives each XCD a contiguous run of image-rows.
// Rows r-1, r, r+1 are then consecutive blocks on the SAME XCD -> L2 hits.
__device__ __forceinline__ int swizzle_row(int i) {
    return (i & (NXCD - 1)) * CHUNK + (i >> 3);
}

// Load cols [c0-1 .. c0+4] of row h into o[6], zero-padded at image edges.
// c0 is pre-clamped to [0, WW-4] by the caller, so all addresses are in-row.
__device__ __forceinline__ void load_row6(const float* __restrict__ img, int h,
                                          int c0, float o[6]) {
    const bool hv = ((unsigned)h < (unsigned)HH);
    const float* r = img + (hv ? h : 0) * WW;
    float4 v = *reinterpret_cast<const float4*>(r + c0);
    float l  = r[max(c0 - 1, 0)];
    float rt = r[min(c0 + 4, WW - 1)];
    o[1] = hv ? v.x : 0.f;
    o[2] = hv ? v.y : 0.f;
    o[3] = hv ? v.z : 0.f;
    o[4] = hv ? v.w : 0.f;
    o[0] = (hv && c0 > 0)      ? l  : 0.f;
    o[5] = (hv && c0 + 4 < WW) ? rt : 0.f;
}

// contrast[i] = center - exact median3x3, for 4 pixels, from 3 row segments.
// Column sort3 (5 ops/col) + med3(max3(lo), med3(mid), min3(hi)) per pixel.
__device__ __forceinline__ void contrast4(const float rp[6], const float rc[6],
                                          const float rn[6], float c[4]) {
    float lo[6], mid[6], hi[6];
#pragma unroll
    for (int j = 0; j < 6; ++j) {
        float a = rp[j], b = rc[j], d = rn[j];
        float t0 = fminf(a, b), t1 = fmaxf(a, b);
        float t2 = fminf(t1, d);
        hi[j]  = fmaxf(t1, d);
        lo[j]  = fminf(t0, t2);
        mid[j] = fmaxf(t0, t2);
    }
#pragma unroll
    for (int i = 0; i < 4; ++i) {
        float mx = fmaxf(fmaxf(lo[i], lo[i + 1]), lo[i + 2]);
        float md = med3f(mid[i], mid[i + 1], mid[i + 2]);
        float mn = fminf(fminf(hi[i], hi[i + 1]), hi[i + 2]);
        c[i] = rc[i + 1] - med3f(mx, md, mn);
    }
}

__device__ __forceinline__ float waveRed(float v) {
#pragma unroll
    for (int o = 32; o > 0; o >>= 1) v += __shfl_down(v, o, 64);
    return v;
}

// Pass 1: per-image sums of {mask, mask*|pred_contrast|, mask*|target_contrast|}.
// One block per image-row; all stencil loads issued up-front (full MLP).
__global__ __launch_bounds__(BLOCK) void pass1(const float* __restrict__ pred,
                                               const float* __restrict__ tgt,
                                               const float* __restrict__ mask,
                                               float* __restrict__ sums) {
    const int f = swizzle_row(blockIdx.x);
    const int b = f / HH;
    const int h = f % HH;
    const int q = threadIdx.x;
    const int c0 = min(q * 4, WW - 4);
    const bool qv = q < QPR;

    const float* pimg = pred + b * IMG;
    const float* timg = tgt  + b * IMG;

    float P0[6], P1[6], P2[6], T0[6], T1[6], T2[6];
    load_row6(pimg, h - 1, c0, P0);
    load_row6(pimg, h,     c0, P1);
    load_row6(pimg, h + 1, c0, P2);
    load_row6(timg, h - 1, c0, T0);
    load_row6(timg, h,     c0, T1);
    load_row6(timg, h + 1, c0, T2);
    float4 m4 = *reinterpret_cast<const float4*>(mask + b * IMG + h * WW + c0);

    float pc[4], tc[4];
    contrast4(P0, P1, P2, pc);
    contrast4(T0, T1, T2, tc);

    float s_m = 0.f, s_p = 0.f, s_t = 0.f;
    float mv[4] = {m4.x, m4.y, m4.z, m4.w};
#pragma unroll
    for (int k = 0; k < 4; ++k) {
        s_m += mv[k];
        s_p += mv[k] * fabsf(pc[k]);
        s_t += mv[k] * fabsf(tc[k]);
    }
    if (!qv) { s_m = 0.f; s_p = 0.f; s_t = 0.f; }

    s_m = waveRed(s_m); s_p = waveRed(s_p); s_t = waveRed(s_t);

    __shared__ float red[3][NWAVE];
    const int lane = threadIdx.x & 63, wid = threadIdx.x >> 6;
    if (lane == 0) { red[0][wid] = s_m; red[1][wid] = s_p; red[2][wid] = s_t; }
    __syncthreads();
    if (threadIdx.x == 0) {
        float a0 = 0.f, a1 = 0.f, a2 = 0.f;
#pragma unroll
        for (int w = 0; w < NWAVE; ++w) { a0 += red[0][w]; a1 += red[1][w]; a2 += red[2][w]; }
        atomicAdd(&sums[b * 3 + 0], a0);
        atomicAdd(&sums[b * 3 + 1], a1);
        atomicAdd(&sums[b * 3 + 2], a2);
    }
}

// Pass 2: per-image sum of |pc/mean_pred - tc/mean_target|.
// NO fences / acquire-release anywhere: the agent-scope release fence +
// acquire RMW tail (round 1) forced a per-block L2 writeback+invalidate
// storm (~285 us). Finalize is a separate kernel; stream order suffices.
__global__ __launch_bounds__(BLOCK) void pass2(const float* __restrict__ pred,
                                               const float* __restrict__ tgt,
                                               const float* __restrict__ sums,
                                               float* __restrict__ acc) {
    const int f = swizzle_row(blockIdx.x);
    const int b = f / HH;
    const int h = f % HH;
    const int q = threadIdx.x;
    const int c0 = min(q * 4, WW - 4);
    const bool qv = q < QPR;

    const float denom  = sums[b * 3 + 0];
    const float inv_mp = denom / sums[b * 3 + 1];
    const float inv_mt = denom / sums[b * 3 + 2];

    const float* pimg = pred + b * IMG;
    const float* timg = tgt  + b * IMG;

    float P0[6], P1[6], P2[6], T0[6], T1[6], T2[6];
    load_row6(pimg, h - 1, c0, P0);
    load_row6(pimg, h,     c0, P1);
    load_row6(pimg, h + 1, c0, P2);
    load_row6(timg, h - 1, c0, T0);
    load_row6(timg, h,     c0, T1);
    load_row6(timg, h + 1, c0, T2);

    float pc[4], tc[4];
    contrast4(P0, P1, P2, pc);
    contrast4(T0, T1, T2, tc);

    float s = 0.f;
#pragma unroll
    for (int k = 0; k < 4; ++k)
        s += fabsf(pc[k] * inv_mp - tc[k] * inv_mt);
    if (!qv) s = 0.f;

    s = waveRed(s);

    __shared__ float red[NWAVE];
    const int lane = threadIdx.x & 63, wid = threadIdx.x >> 6;
    if (lane == 0) red[wid] = s;
    __syncthreads();
    if (threadIdx.x == 0) {
        float a = 0.f;
#pragma unroll
        for (int w = 0; w < NWAVE; ++w) a += red[w];
        atomicAdd(&acc[b], a);
    }
}

__global__ void finalize(const float* __restrict__ sums,
                         const float* __restrict__ acc,
                         float* __restrict__ out) {
    float tm = 0.f, ta = 0.f;
    for (int b = 0; b < BATCH; ++b) { tm += sums[b * 3 + 0]; ta += acc[b]; }
    out[0] = ta / tm;
}

extern "C" void kernel_launch(void* const* d_in, const int* in_sizes, int n_in,
                              void* d_out, int out_size, void* d_ws, size_t ws_size,
                              hipStream_t stream) {
    const float* pred = (const float*)d_in[0];
    const float* tgt  = (const float*)d_in[1];
    const float* mask = (const float*)d_in[2];
    float* out = (float*)d_out;
    float* ws  = (float*)d_ws;  // [0..47] per-image {Sm,Sp,St}; [48..63] per-image loss acc

    hipMemsetAsync(d_ws, 0, 64 * sizeof(float), stream);

    dim3 grid(NBLK), blk(BLOCK);
    pass1<<<grid, blk, 0, stream>>>(pred, tgt, mask, ws);
    pass2<<<grid, blk, 0, stream>>>(pred, tgt, ws, ws + 48);
    finalize<<<1, 1, 0, stream>>>(ws, ws + 48, out);
}

// Round 3
// 155.541 us; speedup vs baseline: 3.1491x; 1.8774x over previous
//
#include <hip/hip_runtime.h>

// Geometry fixed by setup_inputs: [16, 1, 352, 1216] fp32.
#define BATCH 16
#define HH    352
#define WW    1216
#define IMG   (HH * WW)
#define QPR   (WW / 4)       // 304 quads (float4 groups) per row
#define BLOCK 320            // 5 waves; covers one full row (304 quads + 16 idle)
#define NWAVE (BLOCK / 64)
#define NBLK  (BATCH * HH)   // one block per image-row = 5632 (divisible by 8)
#define NXCD  8
#define CHUNK (NBLK / NXCD)  // 704
#define SLOTS 32             // atomic spreading: 352 blocks/image -> 11 RMW/address

// Workspace layout (floats):
//   [0    .. 1535]  p1s: 48 quantities (b*3+i) x 32 slots
//   [1536 .. 1583]  mid: per image {denom, denom/Sp, denom/St}
//   [1600 .. 2111]  acc: 16 images x 32 slots of loss partials
#define WS_P1S 0
#define WS_MID 1536
#define WS_ACC 1600
#define WS_ZERO_BYTES (2112 * 4)

__device__ __forceinline__ float med3f(float a, float b, float c) {
#if defined(__has_builtin) && __has_builtin(__builtin_amdgcn_fmed3f)
    return __builtin_amdgcn_fmed3f(a, b, c);
#else
    return fmaxf(fminf(fmaxf(a, b), c), fminf(a, b));
#endif
}

// Bijective XCD swizzle: hardware assigns block i to XCD i%8, so
// i -> (i%8)*CHUNK + i/8 gives each XCD a contiguous run of image-rows.
// Rows r-1, r, r+1 are then consecutive blocks on the SAME XCD -> L2 hits.
__device__ __forceinline__ int swizzle_row(int i) {
    return (i & (NXCD - 1)) * CHUNK + (i >> 3);
}

// Raw stencil row segment: pure loads, clamped addresses, NO selects.
// Out-of-image rows load row 0 (garbage is masked in fix6 after the barrier).
struct Row6 {
    float4 v;   // cols c0 .. c0+3
    float  l;   // col c0-1 (clamped)
    float  r;   // col c0+4 (clamped)
};

__device__ __forceinline__ Row6 load_raw(const float* __restrict__ img, int h,
                                         int c0) {
    const int hc = ((unsigned)h < (unsigned)HH) ? h : 0;
    const float* rr = img + hc * WW;
    Row6 o;
    o.v = *reinterpret_cast<const float4*>(rr + c0);
    o.l = rr[max(c0 - 1, 0)];
    o.r = rr[min(c0 + 4, WW - 1)];
    return o;
}

// Post-load fix-up: apply zero padding at image edges.
__device__ __forceinline__ void fix6(const Row6& in, int h, int c0, float o[6]) {
    const bool hv = ((unsigned)h < (unsigned)HH);
    o[0] = (hv && c0 > 0)      ? in.l   : 0.f;
    o[1] = hv ? in.v.x : 0.f;
    o[2] = hv ? in.v.y : 0.f;
    o[3] = hv ? in.v.z : 0.f;
    o[4] = hv ? in.v.w : 0.f;
    o[5] = (hv && c0 + 4 < WW) ? in.r   : 0.f;
}

// contrast[i] = center - exact median3x3, for 4 pixels, from 3 row segments.
__device__ __forceinline__ void contrast4(const float rp[6], const float rc[6],
                                          const float rn[6], float c[4]) {
    float lo[6], mid[6], hi[6];
#pragma unroll
    for (int j = 0; j < 6; ++j) {
        float a = rp[j], b = rc[j], d = rn[j];
        float t0 = fminf(a, b), t1 = fmaxf(a, b);
        float t2 = fminf(t1, d);
        hi[j]  = fmaxf(t1, d);
        lo[j]  = fminf(t0, t2);
        mid[j] = fmaxf(t0, t2);
    }
#pragma unroll
    for (int i = 0; i < 4; ++i) {
        float mx = fmaxf(fmaxf(lo[i], lo[i + 1]), lo[i + 2]);
        float md = med3f(mid[i], mid[i + 1], mid[i + 2]);
        float mn = fminf(fminf(hi[i], hi[i + 1]), hi[i + 2]);
        c[i] = rc[i + 1] - med3f(mx, md, mn);
    }
}

__device__ __forceinline__ float waveRed(float v) {
#pragma unroll
    for (int o = 32; o > 0; o >>= 1) v += __shfl_down(v, o, 64);
    return v;
}

// Pass 1: per-image sums of {mask, mask*|pred_contrast|, mask*|target_contrast|}.
// One block per image-row. ALL 19 loads are issued before a sched_barrier(0)
// so the compiler cannot interleave consumers between them (round 2 it did:
// VGPR=24 proved the stencil was serialized into ~6 dependent load batches).
__global__ __launch_bounds__(BLOCK) void pass1(const float* __restrict__ pred,
                                               const float* __restrict__ tgt,
                                               const float* __restrict__ mask,
                                               float* __restrict__ p1s) {
    const int f = swizzle_row(blockIdx.x);
    const int b = f / HH;
    const int h = f % HH;
    const int q = threadIdx.x;
    const int c0 = min(q * 4, WW - 4);
    const bool qv = q < QPR;
    const int slot = blockIdx.x & (SLOTS - 1);

    const float* pimg = pred + b * IMG;
    const float* timg = tgt  + b * IMG;

    Row6 rp0 = load_raw(pimg, h - 1, c0);
    Row6 rp1 = load_raw(pimg, h,     c0);
    Row6 rp2 = load_raw(pimg, h + 1, c0);
    Row6 rt0 = load_raw(timg, h - 1, c0);
    Row6 rt1 = load_raw(timg, h,     c0);
    Row6 rt2 = load_raw(timg, h + 1, c0);
    float4 m4 = *reinterpret_cast<const float4*>(mask + b * IMG + h * WW + c0);
    __builtin_amdgcn_sched_barrier(0);   // all 19 loads in flight before compute

    float P0[6], P1[6], P2[6], T0[6], T1[6], T2[6];
    fix6(rp0, h - 1, c0, P0);
    fix6(rp1, h,     c0, P1);
    fix6(rp2, h + 1, c0, P2);
    fix6(rt0, h - 1, c0, T0);
    fix6(rt1, h,     c0, T1);
    fix6(rt2, h + 1, c0, T2);

    float pc[4], tc[4];
    contrast4(P0, P1, P2, pc);
    contrast4(T0, T1, T2, tc);

    float s_m = 0.f, s_p = 0.f, s_t = 0.f;
    float mv[4] = {m4.x, m4.y, m4.z, m4.w};
#pragma unroll
    for (int k = 0; k < 4; ++k) {
        s_m += mv[k];
        s_p += mv[k] * fabsf(pc[k]);
        s_t += mv[k] * fabsf(tc[k]);
    }
    if (!qv) { s_m = 0.f; s_p = 0.f; s_t = 0.f; }

    s_m = waveRed(s_m); s_p = waveRed(s_p); s_t = waveRed(s_t);

    __shared__ float red[3][NWAVE];
    const int lane = threadIdx.x & 63, wid = threadIdx.x >> 6;
    if (lane == 0) { red[0][wid] = s_m; red[1][wid] = s_p; red[2][wid] = s_t; }
    __syncthreads();
    if (threadIdx.x == 0) {
        float a0 = 0.f, a1 = 0.f, a2 = 0.f;
#pragma unroll
        for (int w = 0; w < NWAVE; ++w) { a0 += red[0][w]; a1 += red[1][w]; a2 += red[2][w]; }
        atomicAdd(&p1s[(b * 3 + 0) * SLOTS + slot], a0);
        atomicAdd(&p1s[(b * 3 + 1) * SLOTS + slot], a1);
        atomicAdd(&p1s[(b * 3 + 2) * SLOTS + slot], a2);
    }
}

// Fold the 32 slots per quantity and precompute pass2's scale factors.
__global__ void reduce_mid(const float* __restrict__ p1s,
                           float* __restrict__ mid) {
    const int t = threadIdx.x;   // 64 threads, 1 block
    __shared__ float sm[48];
    if (t < 48) {
        float a = 0.f;
#pragma unroll
        for (int s = 0; s < SLOTS; ++s) a += p1s[t * SLOTS + s];
        sm[t] = a;
    }
    __syncthreads();
    if (t < BATCH) {
        float denom = sm[t * 3 + 0];
        mid[t * 3 + 0] = denom;
        mid[t * 3 + 1] = denom / sm[t * 3 + 1];
        mid[t * 3 + 2] = denom / sm[t * 3 + 2];
    }
}

// Pass 2: per-image sum of |pc*inv_mp - tc*inv_mt|.
__global__ __launch_bounds__(BLOCK) void pass2(const float* __restrict__ pred,
                                               const float* __restrict__ tgt,
                                               const float* __restrict__ mid,
                                               float* __restrict__ acc) {
    const int f = swizzle_row(blockIdx.x);
    const int b = f / HH;
    const int h = f % HH;
    const int q = threadIdx.x;
    const int c0 = min(q * 4, WW - 4);
    const bool qv = q < QPR;
    const int slot = blockIdx.x & (SLOTS - 1);

    const float inv_mp = mid[b * 3 + 1];
    const float inv_mt = mid[b * 3 + 2];

    const float* pimg = pred + b * IMG;
    const float* timg = tgt  + b * IMG;

    Row6 rp0 = load_raw(pimg, h - 1, c0);
    Row6 rp1 = load_raw(pimg, h,     c0);
    Row6 rp2 = load_raw(pimg, h + 1, c0);
    Row6 rt0 = load_raw(timg, h - 1, c0);
    Row6 rt1 = load_raw(timg, h,     c0);
    Row6 rt2 = load_raw(timg, h + 1, c0);
    __builtin_amdgcn_sched_barrier(0);   // all 18 loads in flight before compute

    float P0[6], P1[6], P2[6], T0[6], T1[6], T2[6];
    fix6(rp0, h - 1, c0, P0);
    fix6(rp1, h,     c0, P1);
    fix6(rp2, h + 1, c0, P2);
    fix6(rt0, h - 1, c0, T0);
    fix6(rt1, h,     c0, T1);
    fix6(rt2, h + 1, c0, T2);

    float pc[4], tc[4];
    contrast4(P0, P1, P2, pc);
    contrast4(T0, T1, T2, tc);

    float s = 0.f;
#pragma unroll
    for (int k = 0; k < 4; ++k)
        s += fabsf(pc[k] * inv_mp - tc[k] * inv_mt);
    if (!qv) s = 0.f;

    s = waveRed(s);

    __shared__ float red[NWAVE];
    const int lane = threadIdx.x & 63, wid = threadIdx.x >> 6;
    if (lane == 0) red[wid] = s;
    __syncthreads();
    if (threadIdx.x == 0) {
        float a = 0.f;
#pragma unroll
        for (int w = 0; w < NWAVE; ++w) a += red[w];
        atomicAdd(&acc[b * SLOTS + slot], a);
    }
}

__global__ void finalize(const float* __restrict__ mid,
                         const float* __restrict__ acc,
                         float* __restrict__ out) {
    const int t = threadIdx.x;   // 64 threads, 1 block
    float a = 0.f;
#pragma unroll
    for (int i = 0; i < (BATCH * SLOTS) / 64; ++i) a += acc[t + i * 64];
    a = waveRed(a);
    if (t == 0) {
        float tm = 0.f;
#pragma unroll
        for (int b = 0; b < BATCH; ++b) tm += mid[b * 3 + 0];
        out[0] = a / tm;
    }
}

extern "C" void kernel_launch(void* const* d_in, const int* in_sizes, int n_in,
                              void* d_out, int out_size, void* d_ws, size_t ws_size,
                              hipStream_t stream) {
    const float* pred = (const float*)d_in[0];
    const float* tgt  = (const float*)d_in[1];
    const float* mask = (const float*)d_in[2];
    float* out = (float*)d_out;
    float* ws  = (float*)d_ws;

    hipMemsetAsync(d_ws, 0, WS_ZERO_BYTES, stream);

    dim3 grid(NBLK), blk(BLOCK);
    pass1<<<grid, blk, 0, stream>>>(pred, tgt, mask, ws + WS_P1S);
    reduce_mid<<<1, 64, 0, stream>>>(ws + WS_P1S, ws + WS_MID);
    pass2<<<grid, blk, 0, stream>>>(pred, tgt, ws + WS_MID, ws + WS_ACC);
    finalize<<<1, 64, 0, stream>>>(ws + WS_MID, ws + WS_ACC, out);
}

// Round 4
// 141.471 us; speedup vs baseline: 3.4622x; 1.0995x over previous
//
#include <hip/hip_runtime.h>

// Geometry fixed by setup_inputs: [16, 1, 352, 1216] fp32.
#define BATCH 16
#define HH    352
#define WW    1216
#define IMG   (HH * WW)
#define QPR   (WW / 4)          // 304 quads (float4 groups) per row
#define BLOCK 320               // 5 waves; covers one full row of quads
#define NWAVE (BLOCK / 64)
#define RPB   2                 // output rows per block (and per thread)
#define SLOTSI (HH / RPB)       // 176 blocks per image, one slot each
#define PADS  192               // slots padded to 3*64 (pads zero-filled)
#define NBLK  (BATCH * SLOTSI)  // 2816 (divisible by 8)
#define NXCD  8
#define CHUNK (NBLK / NXCD)     // 352

// Workspace (floats): [0..12287] p1s = float4[16*192] {Sm,Sp,St,0};
//                     [12288..15359] acc = float[16*192] loss partials.
#define WS_ACC_F 12288

__device__ __forceinline__ float med3f(float a, float b, float c) {
#if defined(__has_builtin) && __has_builtin(__builtin_amdgcn_fmed3f)
    return __builtin_amdgcn_fmed3f(a, b, c);
#else
    return fmaxf(fminf(fmaxf(a, b), c), fminf(a, b));
#endif
}

// Bijective XCD swizzle: HW assigns block i to XCD i%8, so
// i -> (i%8)*CHUNK + i/8 gives each XCD a contiguous run of row-pairs.
// Adjacent row-pairs land on the SAME XCD -> boundary rows are L2 hits.
__device__ __forceinline__ int swz(int i) {
    return (i & (NXCD - 1)) * CHUNK + (i >> 3);
}

// Raw stencil row segment: pure loads, clamped addresses, NO selects.
struct Row6 {
    float4 v;   // cols c0 .. c0+3
    float  l;   // col c0-1 (clamped)
    float  r;   // col c0+4 (clamped)
};

__device__ __forceinline__ Row6 load_raw(const float* __restrict__ img, int h,
                                         int c0) {
    const int hc = min(max(h, 0), HH - 1);
    const float* rr = img + hc * WW;
    Row6 o;
    o.v = *reinterpret_cast<const float4*>(rr + c0);
    o.l = rr[max(c0 - 1, 0)];
    o.r = rr[min(c0 + 4, WW - 1)];
    return o;
}

// Column zero-padding: only the 2 halo scalars need per-lane selects.
__device__ __forceinline__ void unpack(const Row6& in, int c0, float o[6]) {
    o[0] = (c0 > 0) ? in.l : 0.f;
    o[1] = in.v.x; o[2] = in.v.y; o[3] = in.v.z; o[4] = in.v.w;
    o[5] = (c0 + 4 < WW) ? in.r : 0.f;
}

__device__ __forceinline__ void zero6(float o[6]) {
#pragma unroll
    for (int j = 0; j < 6; ++j) o[j] = 0.f;
}

// Two vertically-adjacent rows of 4 contrasts from 4 row segments.
// Column stage: v_min3/v_med3/v_max3 (3 ops/col/triple, fused by backend).
// Pixel stage:  med3(max3(lo), med3(mid), min3(hi)) — exact 3x3 median.
__device__ __forceinline__ void contrast2x4(const float r0[6], const float r1[6],
                                            const float r2[6], const float r3[6],
                                            float cA[4], float cB[4]) {
    float loA[6], miA[6], hiA[6], loB[6], miB[6], hiB[6];
#pragma unroll
    for (int j = 0; j < 6; ++j) {
        loA[j] = fminf(fminf(r0[j], r1[j]), r2[j]);
        hiA[j] = fmaxf(fmaxf(r0[j], r1[j]), r2[j]);
        miA[j] = med3f(r0[j], r1[j], r2[j]);
        loB[j] = fminf(fminf(r1[j], r2[j]), r3[j]);
        hiB[j] = fmaxf(fmaxf(r1[j], r2[j]), r3[j]);
        miB[j] = med3f(r1[j], r2[j], r3[j]);
    }
#pragma unroll
    for (int i = 0; i < 4; ++i) {
        float mxA = fmaxf(fmaxf(loA[i], loA[i + 1]), loA[i + 2]);
        float mdA = med3f(miA[i], miA[i + 1], miA[i + 2]);
        float mnA = fminf(fminf(hiA[i], hiA[i + 1]), hiA[i + 2]);
        cA[i] = r1[i + 1] - med3f(mxA, mdA, mnA);
        float mxB = fmaxf(fmaxf(loB[i], loB[i + 1]), loB[i + 2]);
        float mdB = med3f(miB[i], miB[i + 1], miB[i + 2]);
        float mnB = fminf(fminf(hiB[i], hiB[i + 1]), hiB[i + 2]);
        cB[i] = r2[i + 1] - med3f(mxB, mdB, mnB);
    }
}

__device__ __forceinline__ float waveRed(float v) {
#pragma unroll
    for (int o = 32; o > 0; o >>= 1) v += __shfl_down(v, o, 64);
    return v;
}

// Pass 1: per-image sums of {mask, mask*|pc|, mask*|tc|} over a row-pair.
// All 26 loads issued before sched_barrier(0); plain-store to a unique slot.
__global__ __launch_bounds__(BLOCK) void pass1(const float* __restrict__ pred,
                                               const float* __restrict__ tgt,
                                               const float* __restrict__ mask,
                                               float4* __restrict__ p1s4) {
    const int f  = swz(blockIdx.x);
    const int b  = f / SLOTSI;
    const int rb = f - b * SLOTSI;
    const int h0 = rb * RPB;
    const int q  = threadIdx.x;
    const int c0 = min(q * 4, WW - 4);
    const bool qv = q < QPR;

    const float* pimg = pred + b * IMG;
    const float* timg = tgt  + b * IMG;

    Row6 rp0 = load_raw(pimg, h0 - 1, c0);
    Row6 rp1 = load_raw(pimg, h0,     c0);
    Row6 rp2 = load_raw(pimg, h0 + 1, c0);
    Row6 rp3 = load_raw(pimg, h0 + 2, c0);
    Row6 rt0 = load_raw(timg, h0 - 1, c0);
    Row6 rt1 = load_raw(timg, h0,     c0);
    Row6 rt2 = load_raw(timg, h0 + 1, c0);
    Row6 rt3 = load_raw(timg, h0 + 2, c0);
    const float* mrow = mask + b * IMG + h0 * WW + c0;
    float4 m0 = *reinterpret_cast<const float4*>(mrow);
    float4 m1 = *reinterpret_cast<const float4*>(mrow + WW);
    __builtin_amdgcn_sched_barrier(0);   // all 26 loads in flight before compute

    float P0[6], P1[6], P2[6], P3[6], T0[6], T1[6], T2[6], T3[6];
    unpack(rp0, c0, P0); unpack(rp1, c0, P1);
    unpack(rp2, c0, P2); unpack(rp3, c0, P3);
    unpack(rt0, c0, T0); unpack(rt1, c0, T1);
    unpack(rt2, c0, T2); unpack(rt3, c0, T3);
    if (h0 == 0)        { zero6(P0); zero6(T0); }   // uniform: 16 blocks total
    if (h0 + RPB == HH) { zero6(P3); zero6(T3); }   // uniform: 16 blocks total

    float pcA[4], pcB[4], tcA[4], tcB[4];
    contrast2x4(P0, P1, P2, P3, pcA, pcB);
    contrast2x4(T0, T1, T2, T3, tcA, tcB);

    float mvA[4] = {m0.x, m0.y, m0.z, m0.w};
    float mvB[4] = {m1.x, m1.y, m1.z, m1.w};
    float s_m = 0.f, s_p = 0.f, s_t = 0.f;
#pragma unroll
    for (int k = 0; k < 4; ++k) {
        s_m += mvA[k] + mvB[k];
        s_p += mvA[k] * fabsf(pcA[k]) + mvB[k] * fabsf(pcB[k]);
        s_t += mvA[k] * fabsf(tcA[k]) + mvB[k] * fabsf(tcB[k]);
    }
    if (!qv) { s_m = 0.f; s_p = 0.f; s_t = 0.f; }

    s_m = waveRed(s_m); s_p = waveRed(s_p); s_t = waveRed(s_t);

    __shared__ float red[3][NWAVE];
    const int lane = threadIdx.x & 63, wid = threadIdx.x >> 6;
    if (lane == 0) { red[0][wid] = s_m; red[1][wid] = s_p; red[2][wid] = s_t; }
    __syncthreads();
    if (threadIdx.x == 0) {
        float a0 = 0.f, a1 = 0.f, a2 = 0.f;
#pragma unroll
        for (int w = 0; w < NWAVE; ++w) { a0 += red[0][w]; a1 += red[1][w]; a2 += red[2][w]; }
        p1s4[b * PADS + rb] = make_float4(a0, a1, a2, 0.f);
        if (rb < PADS - SLOTSI)   // zero-fill pad slots so folds are uniform
            p1s4[b * PADS + SLOTSI + rb] = make_float4(0.f, 0.f, 0.f, 0.f);
    }
}

// Pass 2: per-image sum of |pc*inv_mp - tc*inv_mt| over a row-pair.
// Each wave redundantly folds its image's 192 p1s slots (3 float4 loads +
// shfl_xor butterfly) -> no reduce_mid kernel, no extra barrier.
__global__ __launch_bounds__(BLOCK) void pass2(const float* __restrict__ pred,
                                               const float* __restrict__ tgt,
                                               const float4* __restrict__ p1s4,
                                               float* __restrict__ acc) {
    const int f  = swz(blockIdx.x);
    const int b  = f / SLOTSI;
    const int rb = f - b * SLOTSI;
    const int h0 = rb * RPB;
    const int q  = threadIdx.x;
    const int c0 = min(q * 4, WW - 4);
    const bool qv = q < QPR;
    const int lane = threadIdx.x & 63;

    // Fold loads first so the compiler can wait on them with vmcnt(24),
    // keeping the 24 stencil loads in flight during the fold.
    const float4* s4 = p1s4 + b * PADS;
    float4 f0 = s4[lane];
    float4 f1 = s4[lane + 64];
    float4 f2 = s4[lane + 128];

    const float* pimg = pred + b * IMG;
    const float* timg = tgt  + b * IMG;

    Row6 rp0 = load_raw(pimg, h0 - 1, c0);
    Row6 rp1 = load_raw(pimg, h0,     c0);
    Row6 rp2 = load_raw(pimg, h0 + 1, c0);
    Row6 rp3 = load_raw(pimg, h0 + 2, c0);
    Row6 rt0 = load_raw(timg, h0 - 1, c0);
    Row6 rt1 = load_raw(timg, h0,     c0);
    Row6 rt2 = load_raw(timg, h0 + 1, c0);
    Row6 rt3 = load_raw(timg, h0 + 2, c0);
    __builtin_amdgcn_sched_barrier(0);   // all loads in flight before compute

    float sm = f0.x + f1.x + f2.x;
    float sp = f0.y + f1.y + f2.y;
    float st = f0.z + f1.z + f2.z;
#pragma unroll
    for (int o = 32; o > 0; o >>= 1) {
        sm += __shfl_xor(sm, o, 64);
        sp += __shfl_xor(sp, o, 64);
        st += __shfl_xor(st, o, 64);
    }
    const float inv_mp = sm / sp;
    const float inv_mt = sm / st;

    float P0[6], P1[6], P2[6], P3[6], T0[6], T1[6], T2[6], T3[6];
    unpack(rp0, c0, P0); unpack(rp1, c0, P1);
    unpack(rp2, c0, P2); unpack(rp3, c0, P3);
    unpack(rt0, c0, T0); unpack(rt1, c0, T1);
    unpack(rt2, c0, T2); unpack(rt3, c0, T3);
    if (h0 == 0)        { zero6(P0); zero6(T0); }
    if (h0 + RPB == HH) { zero6(P3); zero6(T3); }

    float pcA[4], pcB[4], tcA[4], tcB[4];
    contrast2x4(P0, P1, P2, P3, pcA, pcB);
    contrast2x4(T0, T1, T2, T3, tcA, tcB);

    float s = 0.f;
#pragma unroll
    for (int k = 0; k < 4; ++k) {
        s += fabsf(pcA[k] * inv_mp - tcA[k] * inv_mt);
        s += fabsf(pcB[k] * inv_mp - tcB[k] * inv_mt);
    }
    if (!qv) s = 0.f;

    s = waveRed(s);

    __shared__ float red[NWAVE];
    const int wid = threadIdx.x >> 6;
    if (lane == 0) red[wid] = s;
    __syncthreads();
    if (threadIdx.x == 0) {
        float a = 0.f;
#pragma unroll
        for (int w = 0; w < NWAVE; ++w) a += red[w];
        acc[b * PADS + rb] = a;
        if (rb < PADS - SLOTSI)
            acc[b * PADS + SLOTSI + rb] = 0.f;
    }
}

__global__ __launch_bounds__(BLOCK) void finalize(const float4* __restrict__ p1s4,
                                                  const float* __restrict__ acc,
                                                  float* __restrict__ out) {
    float tm = 0.f, ta = 0.f;
    for (int j = threadIdx.x; j < BATCH * PADS; j += BLOCK) {
        tm += p1s4[j].x;
        ta += acc[j];
    }
    tm = waveRed(tm); ta = waveRed(ta);
    __shared__ float r0[NWAVE], r1[NWAVE];
    const int lane = threadIdx.x & 63, wid = threadIdx.x >> 6;
    if (lane == 0) { r0[wid] = tm; r1[wid] = ta; }
    __syncthreads();
    if (threadIdx.x == 0) {
        float m = 0.f, a = 0.f;
#pragma unroll
        for (int w = 0; w < NWAVE; ++w) { m += r0[w]; a += r1[w]; }
        out[0] = a / m;
    }
}

extern "C" void kernel_launch(void* const* d_in, const int* in_sizes, int n_in,
                              void* d_out, int out_size, void* d_ws, size_t ws_size,
                              hipStream_t stream) {
    const float* pred = (const float*)d_in[0];
    const float* tgt  = (const float*)d_in[1];
    const float* mask = (const float*)d_in[2];
    float* out = (float*)d_out;
    float* ws  = (float*)d_ws;
    float4* p1s4 = (float4*)ws;
    float*  acc  = ws + WS_ACC_F;

    // No memset needed: every workspace slot (incl. pads) is plain-stored.
    dim3 grid(NBLK), blk(BLOCK);
    pass1<<<grid, blk, 0, stream>>>(pred, tgt, mask, p1s4);
    pass2<<<grid, blk, 0, stream>>>(pred, tgt, p1s4, acc);
    finalize<<<1, blk, 0, stream>>>(p1s4, acc, out);
}

// Round 5
// 123.513 us; speedup vs baseline: 3.9656x; 1.1454x over previous
//
#include <hip/hip_runtime.h>

// Geometry fixed by setup_inputs: [16, 1, 352, 1216] fp32.
#define BATCH 16
#define HH    352
#define WW    1216
#define IMG   (HH * WW)
#define QPR   (WW / 4)          // 304 quads (float4 groups) per row
#define BLOCK 320               // 5 waves; covers one full row of quads
#define NWAVE (BLOCK / 64)
#define RPB   2                 // output rows per block (and per thread)
#define SLOTSI (HH / RPB)       // 176 blocks per image, one slot each
#define PADS  192               // slots padded to 3*64 (pads zero-filled)
#define NBLK  (BATCH * SLOTSI)  // 2816 (divisible by 8)
#define NXCD  8
#define CHUNK (NBLK / NXCD)     // 352

// Workspace (floats): [0..12287] p1s = float4[16*192] {Sm,Sp,St,0};
//                     [12288..15359] acc = float[16*192] loss partials.
#define WS_ACC_F 12288

__device__ __forceinline__ float med3f(float a, float b, float c) {
#if defined(__has_builtin) && __has_builtin(__builtin_amdgcn_fmed3f)
    return __builtin_amdgcn_fmed3f(a, b, c);
#else
    return fmaxf(fminf(fmaxf(a, b), c), fminf(a, b));
#endif
}

// Bijective XCD swizzle: HW assigns block i to XCD i%8, so
// i -> (i%8)*CHUNK + i/8 gives each XCD a contiguous run of row-pairs.
__device__ __forceinline__ int swz(int i) {
    return (i & (NXCD - 1)) * CHUNK + (i >> 3);
}

// One coalesced float4 per row segment; NO halo scalar loads (halos come
// from the LDS edge exchange: 16 of the old 26 global loads eliminated).
__device__ __forceinline__ float4 load4(const float* __restrict__ img, int h,
                                        int c0) {
    const int hc = min(max(h, 0), HH - 1);
    return *reinterpret_cast<const float4*>(img + hc * WW + c0);
}

// Assemble the 6-wide window from the quad + LDS-exchanged halos.
__device__ __forceinline__ void mk6(const float4 v, float eL, float eR,
                                    bool lz, bool rz, float o[6]) {
    o[0] = lz ? 0.f : eL;
    o[1] = v.x; o[2] = v.y; o[3] = v.z; o[4] = v.w;
    o[5] = rz ? 0.f : eR;
}

__device__ __forceinline__ void zero6(float o[6]) {
#pragma unroll
    for (int j = 0; j < 6; ++j) o[j] = 0.f;
}

// Two vertically-adjacent rows of 4 contrasts from 4 row segments.
// Column stage: min3/med3/max3 (fused by backend). Exact 3x3 median.
__device__ __forceinline__ void contrast2x4(const float r0[6], const float r1[6],
                                            const float r2[6], const float r3[6],
                                            float cA[4], float cB[4]) {
    float loA[6], miA[6], hiA[6], loB[6], miB[6], hiB[6];
#pragma unroll
    for (int j = 0; j < 6; ++j) {
        loA[j] = fminf(fminf(r0[j], r1[j]), r2[j]);
        hiA[j] = fmaxf(fmaxf(r0[j], r1[j]), r2[j]);
        miA[j] = med3f(r0[j], r1[j], r2[j]);
        loB[j] = fminf(fminf(r1[j], r2[j]), r3[j]);
        hiB[j] = fmaxf(fmaxf(r1[j], r2[j]), r3[j]);
        miB[j] = med3f(r1[j], r2[j], r3[j]);
    }
#pragma unroll
    for (int i = 0; i < 4; ++i) {
        float mxA = fmaxf(fmaxf(loA[i], loA[i + 1]), loA[i + 2]);
        float mdA = med3f(miA[i], miA[i + 1], miA[i + 2]);
        float mnA = fminf(fminf(hiA[i], hiA[i + 1]), hiA[i + 2]);
        cA[i] = r1[i + 1] - med3f(mxA, mdA, mnA);
        float mxB = fmaxf(fmaxf(loB[i], loB[i + 1]), loB[i + 2]);
        float mdB = med3f(miB[i], miB[i + 1], miB[i + 2]);
        float mnB = fminf(fminf(hiB[i], hiB[i + 1]), hiB[i + 2]);
        cB[i] = r2[i + 1] - med3f(mxB, mdB, mnB);
    }
}

__device__ __forceinline__ float waveRed(float v) {
#pragma unroll
    for (int o = 32; o > 0; o >>= 1) v += __shfl_down(v, o, 64);
    return v;
}

// Shared edge-exchange buffer: 8 row-slots (P0..P3, T0..T3) x {v.x, v.w}.
// 8 * 320 * 8 B = 20 KB. 2-way bank aliasing on b64 access is free.

// Pass 1: per-image sums of {mask, mask*|pc|, mask*|tc|} over a row-pair.
__global__ __launch_bounds__(BLOCK) void pass1(const float* __restrict__ pred,
                                               const float* __restrict__ tgt,
                                               const float* __restrict__ mask,
                                               float4* __restrict__ p1s4) {
    const int f  = swz(blockIdx.x);
    const int b  = f / SLOTSI;
    const int rb = f - b * SLOTSI;
    const int h0 = rb * RPB;
    const int q  = threadIdx.x;
    const int c0 = min(q * 4, WW - 4);
    const bool qv = q < QPR;

    const float* pimg = pred + b * IMG;
    const float* timg = tgt  + b * IMG;

    float4 vp[4], vt[4];
    vp[0] = load4(pimg, h0 - 1, c0);
    vp[1] = load4(pimg, h0,     c0);
    vp[2] = load4(pimg, h0 + 1, c0);
    vp[3] = load4(pimg, h0 + 2, c0);
    vt[0] = load4(timg, h0 - 1, c0);
    vt[1] = load4(timg, h0,     c0);
    vt[2] = load4(timg, h0 + 1, c0);
    vt[3] = load4(timg, h0 + 2, c0);
    const float* mrow = mask + b * IMG + h0 * WW + c0;
    float4 m0 = *reinterpret_cast<const float4*>(mrow);
    float4 m1 = *reinterpret_cast<const float4*>(mrow + WW);
    __builtin_amdgcn_sched_barrier(0);   // all 10 global loads in flight

    __shared__ float2 edge[8][BLOCK];
#pragma unroll
    for (int r = 0; r < 4; ++r) {
        edge[r][q]     = make_float2(vp[r].x, vp[r].w);
        edge[r + 4][q] = make_float2(vt[r].x, vt[r].w);
    }
    __syncthreads();

    const int tl = max(q - 1, 0), tr = min(q + 1, BLOCK - 1);
    const bool lz = (q == 0), rz = (q >= QPR - 1);
    float P0[6], P1[6], P2[6], P3[6], T0[6], T1[6], T2[6], T3[6];
    mk6(vp[0], edge[0][tl].y, edge[0][tr].x, lz, rz, P0);
    mk6(vp[1], edge[1][tl].y, edge[1][tr].x, lz, rz, P1);
    mk6(vp[2], edge[2][tl].y, edge[2][tr].x, lz, rz, P2);
    mk6(vp[3], edge[3][tl].y, edge[3][tr].x, lz, rz, P3);
    mk6(vt[0], edge[4][tl].y, edge[4][tr].x, lz, rz, T0);
    mk6(vt[1], edge[5][tl].y, edge[5][tr].x, lz, rz, T1);
    mk6(vt[2], edge[6][tl].y, edge[6][tr].x, lz, rz, T2);
    mk6(vt[3], edge[7][tl].y, edge[7][tr].x, lz, rz, T3);
    if (h0 == 0)        { zero6(P0); zero6(T0); }   // uniform: 16 blocks total
    if (h0 + RPB == HH) { zero6(P3); zero6(T3); }   // uniform: 16 blocks total

    float pcA[4], pcB[4], tcA[4], tcB[4];
    contrast2x4(P0, P1, P2, P3, pcA, pcB);
    contrast2x4(T0, T1, T2, T3, tcA, tcB);

    float mvA[4] = {m0.x, m0.y, m0.z, m0.w};
    float mvB[4] = {m1.x, m1.y, m1.z, m1.w};
    float s_m = 0.f, s_p = 0.f, s_t = 0.f;
#pragma unroll
    for (int k = 0; k < 4; ++k) {
        s_m += mvA[k] + mvB[k];
        s_p += mvA[k] * fabsf(pcA[k]) + mvB[k] * fabsf(pcB[k]);
        s_t += mvA[k] * fabsf(tcA[k]) + mvB[k] * fabsf(tcB[k]);
    }
    if (!qv) { s_m = 0.f; s_p = 0.f; s_t = 0.f; }

    s_m = waveRed(s_m); s_p = waveRed(s_p); s_t = waveRed(s_t);

    __shared__ float red[3][NWAVE];
    const int lane = threadIdx.x & 63, wid = threadIdx.x >> 6;
    if (lane == 0) { red[0][wid] = s_m; red[1][wid] = s_p; red[2][wid] = s_t; }
    __syncthreads();
    if (threadIdx.x == 0) {
        float a0 = 0.f, a1 = 0.f, a2 = 0.f;
#pragma unroll
        for (int w = 0; w < NWAVE; ++w) { a0 += red[0][w]; a1 += red[1][w]; a2 += red[2][w]; }
        p1s4[b * PADS + rb] = make_float4(a0, a1, a2, 0.f);
        if (rb < PADS - SLOTSI)   // zero-fill pad slots so folds are uniform
            p1s4[b * PADS + SLOTSI + rb] = make_float4(0.f, 0.f, 0.f, 0.f);
    }
}

// Pass 2: per-image sum of |pc*inv_mp - tc*inv_mt| over a row-pair.
// Each wave redundantly folds its image's 192 p1s slots -> no mid kernel.
__global__ __launch_bounds__(BLOCK) void pass2(const float* __restrict__ pred,
                                               const float* __restrict__ tgt,
                                               const float4* __restrict__ p1s4,
                                               float* __restrict__ acc) {
    const int f  = swz(blockIdx.x);
    const int b  = f / SLOTSI;
    const int rb = f - b * SLOTSI;
    const int h0 = rb * RPB;
    const int q  = threadIdx.x;
    const int c0 = min(q * 4, WW - 4);
    const bool qv = q < QPR;
    const int lane = threadIdx.x & 63;

    const float4* s4 = p1s4 + b * PADS;
    float4 f0 = s4[lane];
    float4 f1 = s4[lane + 64];
    float4 f2 = s4[lane + 128];

    const float* pimg = pred + b * IMG;
    const float* timg = tgt  + b * IMG;

    float4 vp[4], vt[4];
    vp[0] = load4(pimg, h0 - 1, c0);
    vp[1] = load4(pimg, h0,     c0);
    vp[2] = load4(pimg, h0 + 1, c0);
    vp[3] = load4(pimg, h0 + 2, c0);
    vt[0] = load4(timg, h0 - 1, c0);
    vt[1] = load4(timg, h0,     c0);
    vt[2] = load4(timg, h0 + 1, c0);
    vt[3] = load4(timg, h0 + 2, c0);
    __builtin_amdgcn_sched_barrier(0);   // all 11 global loads in flight

    __shared__ float2 edge[8][BLOCK];
#pragma unroll
    for (int r = 0; r < 4; ++r) {
        edge[r][q]     = make_float2(vp[r].x, vp[r].w);
        edge[r + 4][q] = make_float2(vt[r].x, vt[r].w);
    }

    // Fold while the edge exchange settles (independent of LDS).
    float sm = f0.x + f1.x + f2.x;
    float sp = f0.y + f1.y + f2.y;
    float st = f0.z + f1.z + f2.z;
#pragma unroll
    for (int o = 32; o > 0; o >>= 1) {
        sm += __shfl_xor(sm, o, 64);
        sp += __shfl_xor(sp, o, 64);
        st += __shfl_xor(st, o, 64);
    }
    const float inv_mp = sm / sp;
    const float inv_mt = sm / st;
    __syncthreads();

    const int tl = max(q - 1, 0), tr = min(q + 1, BLOCK - 1);
    const bool lz = (q == 0), rz = (q >= QPR - 1);
    float P0[6], P1[6], P2[6], P3[6], T0[6], T1[6], T2[6], T3[6];
    mk6(vp[0], edge[0][tl].y, edge[0][tr].x, lz, rz, P0);
    mk6(vp[1], edge[1][tl].y, edge[1][tr].x, lz, rz, P1);
    mk6(vp[2], edge[2][tl].y, edge[2][tr].x, lz, rz, P2);
    mk6(vp[3], edge[3][tl].y, edge[3][tr].x, lz, rz, P3);
    mk6(vt[0], edge[4][tl].y, edge[4][tr].x, lz, rz, T0);
    mk6(vt[1], edge[5][tl].y, edge[5][tr].x, lz, rz, T1);
    mk6(vt[2], edge[6][tl].y, edge[6][tr].x, lz, rz, T2);
    mk6(vt[3], edge[7][tl].y, edge[7][tr].x, lz, rz, T3);
    if (h0 == 0)        { zero6(P0); zero6(T0); }
    if (h0 + RPB == HH) { zero6(P3); zero6(T3); }

    float pcA[4], pcB[4], tcA[4], tcB[4];
    contrast2x4(P0, P1, P2, P3, pcA, pcB);
    contrast2x4(T0, T1, T2, T3, tcA, tcB);

    float s = 0.f;
#pragma unroll
    for (int k = 0; k < 4; ++k) {
        s += fabsf(pcA[k] * inv_mp - tcA[k] * inv_mt);
        s += fabsf(pcB[k] * inv_mp - tcB[k] * inv_mt);
    }
    if (!qv) s = 0.f;

    s = waveRed(s);

    __shared__ float red[NWAVE];
    const int wid = threadIdx.x >> 6;
    if (lane == 0) red[wid] = s;
    __syncthreads();
    if (threadIdx.x == 0) {
        float a = 0.f;
#pragma unroll
        for (int w = 0; w < NWAVE; ++w) a += red[w];
        acc[b * PADS + rb] = a;
        if (rb < PADS - SLOTSI)
            acc[b * PADS + SLOTSI + rb] = 0.f;
    }
}

__global__ __launch_bounds__(BLOCK) void finalize(const float4* __restrict__ p1s4,
                                                  const float* __restrict__ acc,
                                                  float* __restrict__ out) {
    float tm = 0.f, ta = 0.f;
    for (int j = threadIdx.x; j < BATCH * PADS; j += BLOCK) {
        tm += p1s4[j].x;
        ta += acc[j];
    }
    tm = waveRed(tm); ta = waveRed(ta);
    __shared__ float r0[NWAVE], r1[NWAVE];
    const int lane = threadIdx.x & 63, wid = threadIdx.x >> 6;
    if (lane == 0) { r0[wid] = tm; r1[wid] = ta; }
    __syncthreads();
    if (threadIdx.x == 0) {
        float m = 0.f, a = 0.f;
#pragma unroll
        for (int w = 0; w < NWAVE; ++w) { m += r0[w]; a += r1[w]; }
        out[0] = a / m;
    }
}

extern "C" void kernel_launch(void* const* d_in, const int* in_sizes, int n_in,
                              void* d_out, int out_size, void* d_ws, size_t ws_size,
                              hipStream_t stream) {
    const float* pred = (const float*)d_in[0];
    const float* tgt  = (const float*)d_in[1];
    const float* mask = (const float*)d_in[2];
    float* out = (float*)d_out;
    float* ws  = (float*)d_ws;
    float4* p1s4 = (float4*)ws;
    float*  acc  = ws + WS_ACC_F;

    // No memset needed: every workspace slot (incl. pads) is plain-stored.
    dim3 grid(NBLK), blk(BLOCK);
    pass1<<<grid, blk, 0, stream>>>(pred, tgt, mask, p1s4);
    pass2<<<grid, blk, 0, stream>>>(pred, tgt, p1s4, acc);
    finalize<<<1, blk, 0, stream>>>(p1s4, acc, out);
}